// Round 8
// baseline (655.136 us; speedup 1.0000x reference)
//
#include <hip/hip_runtime.h>
#include <cstddef>

#define NB 4
#define SEQL 2048
#define DMODEL 768
#define DSTATE 128
#define HEADDIM 64
#define NHEADS 24
#define DINNER 1536
#define CONVDIM 1792
#define DINPROJ 3352
#define BLROWS (NB*SEQL)
#define RMS_EPS 1e-5f
#define Q 128
#define NC (SEQL/Q)
#define BOFF DINNER
#define COFF (DINNER + DSTATE)
#define BK 64

typedef unsigned int uint;
typedef unsigned short ushort;
typedef __attribute__((ext_vector_type(8))) short bf16x8;
typedef __attribute__((ext_vector_type(4))) float f32x4;

// fast transcendentals: v_exp_f32-based (2 instrs vs ~15 for libm expf)
__device__ __forceinline__ float fexp_(float x){ return __expf(x); }
__device__ __forceinline__ float sigmoidf_(float x){ return 1.f/(1.f+__expf(-x)); }
__device__ __forceinline__ float siluf_(float x){ return x * sigmoidf_(x); }
__device__ __forceinline__ float softplusf_(float x){ return x > 20.f ? x : log1pf(__expf(x)); }

__device__ __forceinline__ ushort f2bf(float f){
    union { float f; uint u; } v; v.f = f;
    uint r = (v.u + 0x7FFFu + ((v.u >> 16) & 1u)) >> 16;
    return (ushort)r;
}
__device__ __forceinline__ float bf2f(ushort s){
    union { uint u; float f; } v; v.u = ((uint)s) << 16;
    return v.f;
}
__device__ __forceinline__ uint pack2(float a, float b){
    return (uint)f2bf(a) | ((uint)f2bf(b) << 16);
}
__device__ __forceinline__ void unpack8(uint4 r, float* o){
    o[0]=bf2f((ushort)(r.x&0xffff)); o[1]=bf2f((ushort)(r.x>>16));
    o[2]=bf2f((ushort)(r.y&0xffff)); o[3]=bf2f((ushort)(r.y>>16));
    o[4]=bf2f((ushort)(r.z&0xffff)); o[5]=bf2f((ushort)(r.z>>16));
    o[6]=bf2f((ushort)(r.w&0xffff)); o[7]=bf2f((ushort)(r.w>>16));
}
__device__ __forceinline__ uint packu2(ushort a, ushort b){
    return (uint)a | ((uint)b << 16);
}

#define GLD16(g, l) __builtin_amdgcn_global_load_lds( \
    (const __attribute__((address_space(1))) void*)(g), \
    (__attribute__((address_space(3))) void*)(l), 16, 0, 0)

#define MFMA_BF16(a, b, c) __builtin_amdgcn_mfma_f32_16x16x32_bf16((a), (b), (c), 0, 0, 0)

// ---------------- fp32 -> bf16 cast, two buffers; also zeroes scan counters
__global__ __launch_bounds__(256) void cast2_kernel(
    const float* __restrict__ a, ushort* __restrict__ oa, int n4a,
    const float* __restrict__ b, ushort* __restrict__ ob, int n4b,
    uint* __restrict__ cnt)
{
    const int i = blockIdx.x*256 + threadIdx.x;
    if (blockIdx.x == 0 && threadIdx.x < NB*NHEADS) cnt[threadIdx.x] = 0u;
    if (i < n4a) {
        float4 v = ((const float4*)a)[i];
        ((ushort4*)oa)[i] = make_ushort4(f2bf(v.x), f2bf(v.y), f2bf(v.z), f2bf(v.w));
    } else {
        const int j = i - n4a;
        if (j < n4b) {
            float4 v = ((const float4*)b)[j];
            ((ushort4*)ob)[j] = make_ushort4(f2bf(v.x), f2bf(v.y), f2bf(v.z), f2bf(v.w));
        }
    }
}

// ---------------- MFMA GEMM, fp32 out (out_proj): C = A @ W^T.
// BM=128, BN=64, BK=64. grid = 768 = 3 blocks/CU balanced. (R3-proven)
__global__ __launch_bounds__(256) void gemm_mfma(
    const ushort* __restrict__ A, const ushort* __restrict__ W,
    float* __restrict__ C, int M, int N, int K,
    const float* __restrict__ gptr)
{
    __shared__ __align__(16) ushort sm[2*12288];   // 48 KB
    const int tid = threadIdx.x;
    const int wv = tid >> 6, ln = tid & 63;
    const int id = blockIdx.x;
    const int xcd = id & 7;
    const int local = id >> 3;
    const int m0 = (xcd*8 + (local & 7)) * 128;
    const int n0 = (local >> 3) * 64;
    const int wm = (wv >> 1) * 64, wn = (wv & 1) * 32;

    const int sr = ln >> 3;
    const int scol = ((ln & 7) ^ sr) * 8;
    const ushort* gA[4]; ushort* lA[4];
#pragma unroll
    for (int iss = 0; iss < 4; ++iss) {
        gA[iss] = A + (size_t)(m0 + wv*32 + iss*8 + sr) * K + scol;
        lA[iss] = &sm[(wv*32 + iss*8) * BK];
    }
    const ushort* gB[2]; ushort* lB[2];
#pragma unroll
    for (int iss = 0; iss < 2; ++iss) {
        gB[iss] = W + (size_t)(n0 + wv*16 + iss*8 + sr) * K + scol;
        lB[iss] = &sm[8192 + (wv*16 + iss*8) * BK];
    }

    f32x4 acc[4][2];
#pragma unroll
    for (int i = 0; i < 4; ++i)
#pragma unroll
        for (int j = 0; j < 2; ++j) acc[i][j] = (f32x4){0.f, 0.f, 0.f, 0.f};

    const int fr = ln & 15;
    const int fq = ln >> 4;
    const int nt = K / BK;

#pragma unroll
    for (int iss = 0; iss < 4; ++iss) GLD16(gA[iss], lA[iss]);
#pragma unroll
    for (int iss = 0; iss < 2; ++iss) GLD16(gB[iss], lB[iss]);

    for (int kt = 0; kt < nt; ++kt) {
        if (kt + 1 < nt) {
            const int so = ((kt + 1) & 1) * 12288;
            const int ko = (kt + 1) * BK;
#pragma unroll
            for (int iss = 0; iss < 4; ++iss) GLD16(gA[iss] + ko, lA[iss] + so);
#pragma unroll
            for (int iss = 0; iss < 2; ++iss) GLD16(gB[iss] + ko, lB[iss] + so);
            asm volatile("s_waitcnt vmcnt(6)" ::: "memory");
        } else {
            asm volatile("s_waitcnt vmcnt(0)" ::: "memory");
        }
        __builtin_amdgcn_s_barrier();
        const ushort* As = sm + (kt & 1) * 12288;
        const ushort* Bs = As + 8192;
#pragma unroll
        for (int kh = 0; kh < 2; ++kh) {
            const int sw = ((kh*4 + fq) ^ (fr & 7)) * 8;
            bf16x8 af[4], bfr[2];
#pragma unroll
            for (int i = 0; i < 4; ++i)
                af[i] = *(const bf16x8*)&As[(wm + i*16 + fr)*BK + sw];
#pragma unroll
            for (int j = 0; j < 2; ++j)
                bfr[j] = *(const bf16x8*)&Bs[(wn + j*16 + fr)*BK + sw];
#pragma unroll
            for (int i = 0; i < 4; ++i)
#pragma unroll
                for (int j = 0; j < 2; ++j)
                    acc[i][j] = MFMA_BF16(af[i], bfr[j], acc[i][j]);
        }
        __builtin_amdgcn_s_barrier();
    }

    float scale = 1.f;
    if (gptr) scale = sigmoidf_(*gptr);
    const int cn = ln & 15;
    const int cr = (ln >> 4) * 4;
#pragma unroll
    for (int i = 0; i < 4; ++i) {
        const int mb = m0 + wm + i*16 + cr;
#pragma unroll
        for (int j = 0; j < 2; ++j) {
            const int n = n0 + wn + j*16 + cn;
            if (n < N) {
                float* cp = C + (size_t)mb * N + n;
                cp[0*(size_t)N] = acc[i][j].x * scale;
                cp[1*(size_t)N] = acc[i][j].y * scale;
                cp[2*(size_t)N] = acc[i][j].z * scale;
                cp[3*(size_t)N] = acc[i][j].w * scale;
            }
        }
    }
}

// ---------------- MFMA GEMM, bf16 out via LDS repack (in_proj); dt cols -> fp32 dtraw.
// R3-proven 128x128 / BK=64 / 64 KB dbuf / vmcnt(8) / swizzled repack (0 conflicts).
__global__ __launch_bounds__(256) void gemm_mfma_bf16o(
    const ushort* __restrict__ A, const ushort* __restrict__ W,
    ushort* __restrict__ C, float* __restrict__ dtraw, int M, int N, int K)
{
    __shared__ __align__(16) ushort sm[2*128*BK*2];   // 64 KB staging; repack aliases
    const int tid = threadIdx.x;
    const int wv = tid >> 6, ln = tid & 63;
    const int id = blockIdx.x;
    const int xcd = id & 7;
    const int local = id >> 3;
    const int m0 = (xcd*8 + (local & 7)) * 128;
    const int n0 = (local >> 3) * 128;
    const int wm = (wv >> 1) * 64, wn = (wv & 1) * 64;

    const int sr = ln >> 3;
    const int scol = ((ln & 7) ^ sr) * 8;
    const ushort* gA[4]; const ushort* gB[4];
    ushort* lA[4]; ushort* lB[4];
#pragma unroll
    for (int iss = 0; iss < 4; ++iss) {
        const int ra = m0 + wv*32 + iss*8 + sr;
        gA[iss] = A + (size_t)ra * K + scol;
        int rb = n0 + wv*32 + iss*8 + sr; if (rb >= N) rb = N - 1;
        gB[iss] = W + (size_t)rb * K + scol;
        lA[iss] = &sm[(wv*32 + iss*8) * BK];
        lB[iss] = &sm[8192 + (wv*32 + iss*8) * BK];
    }

    f32x4 acc[4][4];
#pragma unroll
    for (int i = 0; i < 4; ++i)
#pragma unroll
        for (int j = 0; j < 4; ++j) acc[i][j] = (f32x4){0.f, 0.f, 0.f, 0.f};

    const int fr = ln & 15;
    const int fq = ln >> 4;
    const int nt = K / BK;

#pragma unroll
    for (int iss = 0; iss < 4; ++iss) {
        GLD16(gA[iss], lA[iss]);
        GLD16(gB[iss], lB[iss]);
    }

    for (int kt = 0; kt < nt; ++kt) {
        if (kt + 1 < nt) {
            const int so = ((kt + 1) & 1) * 16384;
            const int ko = (kt + 1) * BK;
#pragma unroll
            for (int iss = 0; iss < 4; ++iss) {
                GLD16(gA[iss] + ko, lA[iss] + so);
                GLD16(gB[iss] + ko, lB[iss] + so);
            }
            asm volatile("s_waitcnt vmcnt(8)" ::: "memory");
        } else {
            asm volatile("s_waitcnt vmcnt(0)" ::: "memory");
        }
        __builtin_amdgcn_s_barrier();
        const ushort* As = sm + (kt & 1) * 16384;
        const ushort* Bs = As + 8192;
#pragma unroll
        for (int kh = 0; kh < 2; ++kh) {
            const int sw = ((kh*4 + fq) ^ (fr & 7)) * 8;
            bf16x8 af[4], bfr[4];
#pragma unroll
            for (int i = 0; i < 4; ++i)
                af[i] = *(const bf16x8*)&As[(wm + i*16 + fr)*BK + sw];
#pragma unroll
            for (int j = 0; j < 4; ++j)
                bfr[j] = *(const bf16x8*)&Bs[(wn + j*16 + fr)*BK + sw];
#pragma unroll
            for (int i = 0; i < 4; ++i)
#pragma unroll
                for (int j = 0; j < 4; ++j)
                    acc[i][j] = MFMA_BF16(af[i], bfr[j], acc[i][j]);
        }
        __builtin_amdgcn_s_barrier();
    }

    const int cn = ln & 15;
    const int cr = (ln >> 4) * 4;
    __syncthreads();                       // staging LDS dead -> repack
    ushort* rp = sm + wv*4096;             // 64 rows x 64 cols per wave, XOR-swizzled
#pragma unroll
    for (int i = 0; i < 4; ++i)
#pragma unroll
        for (int j = 0; j < 4; ++j) {
            const int colb = j*16 + cn;
#pragma unroll
            for (int r = 0; r < 4; ++r) {
                const int row = i*16 + cr + r;
                rp[row*64 + (((colb >> 3) ^ (row & 7)) * 8) + (colb & 7)] = f2bf(acc[i][j][r]);
            }
        }
    __syncthreads();
#pragma unroll
    for (int k2 = 0; k2 < 8; ++k2) {
        const int row = k2*8 + (ln >> 3);
        const int cg = ln & 7;
        uint4 v = *(const uint4*)&rp[row*64 + ((cg ^ (row & 7)) * 8)];
        const int gm = m0 + wm + row;
        const int gn = n0 + wn + cg*8;
        if (gn + 8 <= N)
            *(uint4*)(C + (size_t)gm*N + gn) = v;
    }
    if (n0 + 128 > N) {
#pragma unroll
        for (int i = 0; i < 4; ++i) {
            const int mb = m0 + wm + i*16 + cr;
#pragma unroll
            for (int j = 0; j < 4; ++j) {
                const int col = (n0 + wn + j*16 + cn) - (N - 24);
                if (col >= 0 && col < 24) {
                    dtraw[(size_t)(mb+0)*24 + col] = acc[i][j].x;
                    dtraw[(size_t)(mb+1)*24 + col] = acc[i][j].y;
                    dtraw[(size_t)(mb+2)*24 + col] = acc[i][j].z;
                    dtraw[(size_t)(mb+3)*24 + col] = acc[i][j].w;
                }
            }
        }
    }
}

// ---------------- FUSED: causal depthwise conv1d+silu  ||  dt softplus+cumsum
__global__ __launch_bounds__(448) void conv_dtscan_kernel(
    const ushort* __restrict__ zx, const float* __restrict__ conv_w,
    const float* __restrict__ conv_b, ushort* __restrict__ xconv,
    const float* __restrict__ dtraw, const float* __restrict__ dt_bias,
    const float* __restrict__ A_log, float* __restrict__ dtc,
    float* __restrict__ clog)
{
    if (blockIdx.x < BLROWS/16) {
        // ---- conv: 16 l-positions per block, sliding register window
        const int c4 = threadIdx.x;
        const int bl0 = blockIdx.x * 16;
        const int l0 = bl0 & (SEQL - 1);
        float w[4][4];
#pragma unroll
        for (int j = 0; j < 4; ++j) {
            float4 wr = *(const float4*)(conv_w + (c4*4 + j)*4);
            w[j][0]=wr.x; w[j][1]=wr.y; w[j][2]=wr.z; w[j][3]=wr.w;
        }
        const float4 bias = *(const float4*)(conv_b + c4*4);
        const ushort* src = zx + DINNER + (size_t)c4*4;
        ushort* dst = xconv + (size_t)c4*4;

        float h0[4], h1[4], h2[4];
        if (l0 == 0) {
#pragma unroll
            for (int ch = 0; ch < 4; ++ch) { h0[ch]=0.f; h1[ch]=0.f; h2[ch]=0.f; }
        } else {
            ushort4 a = *(const ushort4*)(src + (size_t)(bl0-3)*DINPROJ);
            ushort4 b = *(const ushort4*)(src + (size_t)(bl0-2)*DINPROJ);
            ushort4 c = *(const ushort4*)(src + (size_t)(bl0-1)*DINPROJ);
            h0[0]=bf2f(a.x); h0[1]=bf2f(a.y); h0[2]=bf2f(a.z); h0[3]=bf2f(a.w);
            h1[0]=bf2f(b.x); h1[1]=bf2f(b.y); h1[2]=bf2f(b.z); h1[3]=bf2f(b.w);
            h2[0]=bf2f(c.x); h2[1]=bf2f(c.y); h2[2]=bf2f(c.z); h2[3]=bf2f(c.w);
        }
#pragma unroll
        for (int t = 0; t < 16; ++t) {
            ushort4 xv = *(const ushort4*)(src + (size_t)(bl0 + t)*DINPROJ);
            float h3[4] = {bf2f(xv.x), bf2f(xv.y), bf2f(xv.z), bf2f(xv.w)};
            float s0 = fmaf(h3[0], w[0][3], fmaf(h2[0], w[0][2], fmaf(h1[0], w[0][1], fmaf(h0[0], w[0][0], bias.x))));
            float s1 = fmaf(h3[1], w[1][3], fmaf(h2[1], w[1][2], fmaf(h1[1], w[1][1], fmaf(h0[1], w[1][0], bias.y))));
            float s2 = fmaf(h3[2], w[2][3], fmaf(h2[2], w[2][2], fmaf(h1[2], w[2][1], fmaf(h0[2], w[2][0], bias.z))));
            float s3 = fmaf(h3[3], w[3][3], fmaf(h2[3], w[3][2], fmaf(h1[3], w[3][1], fmaf(h0[3], w[3][0], bias.w))));
            ushort4 o = make_ushort4(f2bf(siluf_(s0)), f2bf(siluf_(s1)),
                                     f2bf(siluf_(s2)), f2bf(siluf_(s3)));
            *(ushort4*)(dst + (size_t)(bl0 + t)*CONVDIM) = o;
#pragma unroll
            for (int ch = 0; ch < 4; ++ch) { h0[ch]=h1[ch]; h1[ch]=h2[ch]; h2[ch]=h3[ch]; }
        }
    } else {
        // ---- dtscan: id = c + NC*(h + NHEADS*b)
        const int id = blockIdx.x - BLROWS/16;
        const int c = id & (NC - 1);
        const int h = (id >> 4) % NHEADS;
        const int b = id / (NC * NHEADS);
        const int t = threadIdx.x;
        __shared__ float w0tot;
        float v = 0.f, dtv = 0.f;
        if (t < 128) {
            const int bl = b*SEQL + c*Q + t;
            float draw = dtraw[(size_t)bl*24 + h] + dt_bias[h];
            dtv = softplusf_(draw);
            v = -fexp_(A_log[h]) * dtv;
            const int lane = t & 63;
#pragma unroll
            for (int off = 1; off < 64; off <<= 1) {
                float u = __shfl_up(v, off);
                if (lane >= off) v += u;
            }
            if (t == 63) w0tot = v;
        }
        __syncthreads();
        if (t < 128) {
            if (t >= 64) v += w0tot;
            const int idx = (b*NHEADS + h)*SEQL + c*Q + t;
            dtc[idx] = dtv;
            clog[idx] = v;
        }
    }
}

// ---------------- FUSED: gcb (G = C.B^T)  ||  locstate (+tail-fused chunkscan)
// Blocks [0, 2*NC*NB): gcb. Blocks [+, +NC*NHEADS*NB): locstate.
// After a (b,h)'s 16 locstate blocks complete (device-scope counter), the LAST
// one performs the sequential prefix scan over its 16 chunk-states in place.
// 95/96 scans overlap still-running blocks; only the final (b,h)'s is exposed.
#define ASTR 40
#define BSTR 40
__global__ __launch_bounds__(256) void gcb_locstate_kernel(
    const ushort* __restrict__ xconv, ushort* __restrict__ G,
    const float* __restrict__ dtc, const float* __restrict__ clog,
    ushort* __restrict__ Sloc, uint* __restrict__ cnt)
{
    __shared__ __align__(16) char smraw[15872];
    const int tid = threadIdx.x;
    const int wv = tid >> 6, ln = tid & 63;
    const int fr = ln & 15, fq = ln >> 4, fk = fq*8;

    if (blockIdx.x < 2*NC*NB) {
        // ---- gcb: id = thalf + 2*(c + NC*b)
        ushort* Ca = (ushort*)smraw;                 // 64*32
        ushort* Bb = (ushort*)(smraw + 4096);        // 128*32
        const int id = blockIdx.x;
        const int thalf = id & 1;
        const int c = (id >> 1) & (NC - 1);
        const int b = id >> 5;
        const int bl0 = b*SEQL + c*Q;
        const int th0 = thalf*64;

        const int sat = tid & 63,  sac = (tid >> 6)*8;
        const int sbt = tid & 127, sbh = (tid >> 7)*16;

        f32x4 acc[4][2];
#pragma unroll
        for (int i = 0; i < 4; ++i)
#pragma unroll
            for (int j = 0; j < 2; ++j) acc[i][j] = (f32x4){0.f,0.f,0.f,0.f};

        for (int ks = 0; ks < 4; ++ks) {
            uint4 av = *(const uint4*)(xconv + (size_t)(bl0 + th0 + sat)*CONVDIM + COFF + ks*32 + sac);
            const ushort* br = xconv + (size_t)(bl0 + sbt)*CONVDIM + BOFF + ks*32 + sbh;
            uint4 bv0 = *(const uint4*)br;
            uint4 bv1 = *(const uint4*)(br + 8);
            __syncthreads();
            *(uint4*)&Ca[sat*32 + sac] = av;
            *(uint4*)&Bb[sbt*32 + sbh] = bv0;
            *(uint4*)&Bb[sbt*32 + sbh + 8] = bv1;
            __syncthreads();
            bf16x8 av_[4], bv_[2];
#pragma unroll
            for (int i = 0; i < 4; ++i)
                av_[i] = *(const bf16x8*)&Ca[(i*16 + fr)*32 + fk];
#pragma unroll
            for (int j = 0; j < 2; ++j)
                bv_[j] = *(const bf16x8*)&Bb[(wv*32 + j*16 + fr)*32 + fk];
#pragma unroll
            for (int i = 0; i < 4; ++i)
#pragma unroll
                for (int j = 0; j < 2; ++j)
                    acc[i][j] = MFMA_BF16(av_[i], bv_[j], acc[i][j]);
        }
        ushort* gout = G + (size_t)(b*NC + c)*(Q*Q);
#pragma unroll
        for (int i = 0; i < 4; ++i) {
#pragma unroll
            for (int j = 0; j < 2; ++j) {
                const int s = wv*32 + j*16 + fr;
#pragma unroll
                for (int r = 0; r < 4; ++r) {
                    const int t = th0 + i*16 + fq*4 + r;
                    gout[t*Q + s] = f2bf(acc[i][j][r]);
                }
            }
        }
    } else {
        // ---- locstate (R6 pipelined): id = c + NC*(h + NHEADS*b)
        ushort* Ab = (ushort*)smraw;                 // 64*ASTR
        float* sw = (float*)(smraw + 15360);         // 128 floats
        ushort* Bb = (ushort*)(smraw + 5120);        // 128*BSTR
        __shared__ uint is_last;
        const int id = blockIdx.x - 2*NC*NB;
        const int c = id & (NC - 1);
        const int h = (id >> 4) % NHEADS;
        const int b = id / (NC * NHEADS);
        const int bh = b*NHEADS + h;
        const int bl0 = b*SEQL + c*Q;

        if (tid < Q) {
            const float ce = clog[(size_t)bh*SEQL + c*Q + (Q-1)];
            const float cs = clog[(size_t)bh*SEQL + c*Q + tid];
            sw[tid] = dtc[(size_t)bh*SEQL + c*Q + tid] * fexp_(ce - cs);
        }

        f32x4 acc[4][2];
#pragma unroll
        for (int i = 0; i < 4; ++i)
#pragma unroll
            for (int j = 0; j < 2; ++j) acc[i][j] = (f32x4){0.f,0.f,0.f,0.f};

        const int ap = tid & 63, aoct = tid >> 6;
        const int bn = tid & 127, bhalf = tid >> 7;

        ushort xrc[8]; ushort buc[16];
#pragma unroll
        for (int j = 0; j < 8; ++j)
            xrc[j] = xconv[(size_t)(bl0 + aoct*8 + j)*CONVDIM + h*HEADDIM + ap];
#pragma unroll
        for (int j = 0; j < 16; ++j)
            buc[j] = xconv[(size_t)(bl0 + bhalf*16 + j)*CONVDIM + BOFF + bn];

        __syncthreads();   // sw visible; raw(0) in regs

        uint4 pkA, pkB0, pkB1;
        {
            float xv[8];
#pragma unroll
            for (int j = 0; j < 8; ++j) xv[j] = bf2f(xrc[j]) * sw[aoct*8 + j];
            pkA = make_uint4(pack2(xv[0],xv[1]), pack2(xv[2],xv[3]),
                             pack2(xv[4],xv[5]), pack2(xv[6],xv[7]));
            pkB0 = make_uint4(packu2(buc[0],buc[1]), packu2(buc[2],buc[3]),
                              packu2(buc[4],buc[5]), packu2(buc[6],buc[7]));
            pkB1 = make_uint4(packu2(buc[8],buc[9]), packu2(buc[10],buc[11]),
                              packu2(buc[12],buc[13]), packu2(buc[14],buc[15]));
        }
#pragma unroll
        for (int j = 0; j < 8; ++j)
            xrc[j] = xconv[(size_t)(bl0 + 32 + aoct*8 + j)*CONVDIM + h*HEADDIM + ap];
#pragma unroll
        for (int j = 0; j < 16; ++j)
            buc[j] = xconv[(size_t)(bl0 + 32 + bhalf*16 + j)*CONVDIM + BOFF + bn];

#pragma unroll
        for (int ks = 0; ks < 4; ++ks) {
            if (ks > 0) __syncthreads();
            *(uint4*)&Ab[ap*ASTR + aoct*8] = pkA;
            *(uint4*)&Bb[bn*BSTR + bhalf*16] = pkB0;
            *(uint4*)&Bb[bn*BSTR + bhalf*16 + 8] = pkB1;
            __syncthreads();
            if (ks < 3) {
                float xv[8];
#pragma unroll
                for (int j = 0; j < 8; ++j) xv[j] = bf2f(xrc[j]) * sw[(ks+1)*32 + aoct*8 + j];
                pkA = make_uint4(pack2(xv[0],xv[1]), pack2(xv[2],xv[3]),
                                 pack2(xv[4],xv[5]), pack2(xv[6],xv[7]));
                pkB0 = make_uint4(packu2(buc[0],buc[1]), packu2(buc[2],buc[3]),
                                  packu2(buc[4],buc[5]), packu2(buc[6],buc[7]));
                pkB1 = make_uint4(packu2(buc[8],buc[9]), packu2(buc[10],buc[11]),
                                  packu2(buc[12],buc[13]), packu2(buc[14],buc[15]));
                if (ks < 2) {
#pragma unroll
                    for (int j = 0; j < 8; ++j)
                        xrc[j] = xconv[(size_t)(bl0 + (ks+2)*32 + aoct*8 + j)*CONVDIM + h*HEADDIM + ap];
#pragma unroll
                    for (int j = 0; j < 16; ++j)
                        buc[j] = xconv[(size_t)(bl0 + (ks+2)*32 + bhalf*16 + j)*CONVDIM + BOFF + bn];
                }
            }
            bf16x8 af[4], bf[2];
#pragma unroll
            for (int i = 0; i < 4; ++i)
                af[i] = *(const bf16x8*)&Ab[(i*16 + fr)*ASTR + fk];
#pragma unroll
            for (int j = 0; j < 2; ++j)
                bf[j] = *(const bf16x8*)&Bb[(wv*32 + j*16 + fr)*BSTR + fk];
#pragma unroll
            for (int i = 0; i < 4; ++i)
#pragma unroll
                for (int j = 0; j < 2; ++j)
                    acc[i][j] = MFMA_BF16(af[i], bf[j], acc[i][j]);
        }
        ushort* dst = Sloc + (size_t)((b*NC + c)*NHEADS + h) * (HEADDIM*DSTATE);
#pragma unroll
        for (int i = 0; i < 4; ++i) {
#pragma unroll
            for (int j = 0; j < 2; ++j) {
                const int n = wv*32 + j*16 + fr;
#pragma unroll
                for (int r = 0; r < 4; ++r) {
                    const int p = i*16 + fq*4 + r;
                    dst[p*DSTATE + n] = f2bf(acc[i][j][r]);
                }
            }
        }

        // ---- tail-fused chunkscan: last-arriving chunk block of (b,h) scans.
        __threadfence();                       // release: Sloc writes device-visible
        __syncthreads();                       // all threads fenced before the add
        if (tid == 0)
            is_last = (atomicAdd(&cnt[bh], 1u) == (uint)(NC - 1));
        __syncthreads();
        if (is_last) {
            __threadfence();                   // acquire: see other blocks' Sloc
            const int pr = tid >> 4;           // 0..15
            const int n0 = (tid & 15) * 8;
            float st[4][8];
#pragma unroll
            for (int pg = 0; pg < 4; ++pg)
#pragma unroll
                for (int j = 0; j < 8; ++j) st[pg][j] = 0.f;

            uint4 nxt[4];
            {
                ushort* base0 = Sloc + (size_t)((b*NC + 0)*NHEADS + h) * (HEADDIM*DSTATE);
#pragma unroll
                for (int pg = 0; pg < 4; ++pg)
                    nxt[pg] = *(uint4*)(base0 + (pg*16 + pr)*DSTATE + n0);
            }
            for (int cc = 0; cc < NC; ++cc) {
                uint4 cur[4];
#pragma unroll
                for (int pg = 0; pg < 4; ++pg) cur[pg] = nxt[pg];
                ushort* base = Sloc + (size_t)((b*NC + cc)*NHEADS + h) * (HEADDIM*DSTATE);
                if (cc + 1 < NC) {
                    ushort* bn_ = Sloc + (size_t)((b*NC + cc + 1)*NHEADS + h) * (HEADDIM*DSTATE);
#pragma unroll
                    for (int pg = 0; pg < 4; ++pg)
                        nxt[pg] = *(uint4*)(bn_ + (pg*16 + pr)*DSTATE + n0);
                }
                const float tc = fexp_(clog[(size_t)bh*SEQL + cc*Q + (Q-1)]);
#pragma unroll
                for (int pg = 0; pg < 4; ++pg) {
                    float lv[8];
                    unpack8(cur[pg], lv);
                    uint4 pre = make_uint4(pack2(st[pg][0],st[pg][1]), pack2(st[pg][2],st[pg][3]),
                                           pack2(st[pg][4],st[pg][5]), pack2(st[pg][6],st[pg][7]));
                    *(uint4*)(base + (pg*16 + pr)*DSTATE + n0) = pre;
#pragma unroll
                    for (int j = 0; j < 8; ++j) st[pg][j] = fmaf(tc, st[pg][j], lv[j]);
                }
            }
            __threadfence();                   // release scanned states for ychunk
        }
    }
}

// ---------------- Y = causal(G.W)@X + exp(clog)*C@Sp^T + D*x  — MFMA, bf16 out
__global__ __launch_bounds__(256) void ychunk_mfma(
    const ushort* __restrict__ xconv, const float* __restrict__ dtc,
    const float* __restrict__ clog, const ushort* __restrict__ G,
    const ushort* __restrict__ Sp, const float* __restrict__ Dv,
    ushort* __restrict__ ybf)
{
    __shared__ __align__(16) ushort smu[8192];
    ushort* Ab = smu;
    ushort* Bb = smu + 4096;
    __shared__ float s_clog[Q];
    __shared__ float s_dtc[Q];
    const int c = blockIdx.x, h = blockIdx.y, b = blockIdx.z;
    const int tid = threadIdx.x;
    const int wv = tid >> 6, ln = tid & 63;
    const int bh = b*NHEADS + h;
    const int bl0 = b*SEQL + c*Q;
    const int fr = ln & 15, fq = ln >> 4, fk = fq*8;

    if (tid < Q) {
        s_clog[tid] = clog[(size_t)bh*SEQL + c*Q + tid];
        s_dtc[tid]  = dtc [(size_t)bh*SEQL + c*Q + tid];
    }

    f32x4 acc[2][4];
#pragma unroll
    for (int i = 0; i < 2; ++i)
#pragma unroll
        for (int j = 0; j < 4; ++j) acc[i][j] = (f32x4){0.f,0.f,0.f,0.f};

    const int sgt = tid & 127, sgh = (tid >> 7)*16;
    const int sbp = tid & 63,  sbc = (tid >> 6)*8;
    const ushort* spb = Sp + (size_t)((b*NC + c)*NHEADS + h)*(HEADDIM*DSTATE);

    // phase 1: acc = C @ Sp^T  (pipelined loads)
    uint4 cv0c = *(const uint4*)(xconv + (size_t)(bl0 + sgt)*CONVDIM + COFF + sgh);
    uint4 cv1c = *(const uint4*)(xconv + (size_t)(bl0 + sgt)*CONVDIM + COFF + sgh + 8);
    uint4 svc  = *(const uint4*)(spb + sbp*DSTATE + sbc);
#pragma unroll
    for (int ks = 0; ks < 4; ++ks) {
        __syncthreads();
        *(uint4*)&Ab[sgt*32 + sgh]     = cv0c;
        *(uint4*)&Ab[sgt*32 + sgh + 8] = cv1c;
        *(uint4*)&Bb[sbp*32 + sbc] = svc;
        if (ks < 3) {
            const ushort* cr = xconv + (size_t)(bl0 + sgt)*CONVDIM + COFF + (ks+1)*32 + sgh;
            cv0c = *(const uint4*)cr;
            cv1c = *(const uint4*)(cr + 8);
            svc  = *(const uint4*)(spb + sbp*DSTATE + (ks+1)*32 + sbc);
        }
        __syncthreads();
        bf16x8 af[2], bv[4];
        af[0] = *(const bf16x8*)&Ab[(wv*32 +      fr)*32 + fk];
        af[1] = *(const bf16x8*)&Ab[(wv*32 + 16 + fr)*32 + fk];
#pragma unroll
        for (int j = 0; j < 4; ++j)
            bv[j] = *(const bf16x8*)&Bb[(j*16 + fr)*32 + fk];
#pragma unroll
        for (int i = 0; i < 2; ++i)
#pragma unroll
            for (int j = 0; j < 4; ++j)
                acc[i][j] = MFMA_BF16(af[i], bv[j], acc[i][j]);
    }

    // raw(0) for phase 2 (hides under the rescale VALU below)
    const ushort* gp = G + (size_t)(b*NC + c)*(Q*Q);
    uint4 g0c = *(const uint4*)(gp + sgt*Q + sgh);
    uint4 g1c = *(const uint4*)(gp + sgt*Q + sgh + 8);
    ushort xuc[8];
#pragma unroll
    for (int j = 0; j < 8; ++j)
        xuc[j] = xconv[(size_t)(bl0 + sbc + j)*CONVDIM + h*HEADDIM + sbp];

#pragma unroll
    for (int i = 0; i < 2; ++i) {
        const int tb = wv*32 + i*16 + fq*4;
        float e0 = fexp_(s_clog[tb+0]), e1 = fexp_(s_clog[tb+1]);
        float e2 = fexp_(s_clog[tb+2]), e3 = fexp_(s_clog[tb+3]);
#pragma unroll
        for (int j = 0; j < 4; ++j) {
            acc[i][j].x *= e0; acc[i][j].y *= e1; acc[i][j].z *= e2; acc[i][j].w *= e3;
        }
    }

    const float ct = s_clog[sgt];

    uint4 pkA0, pkA1, pkB;
#define YPK(KS) do { \
        float gvals[16]; \
        unpack8(g0c, gvals); \
        unpack8(g1c, gvals + 8); \
        ushort gw[16]; \
        _Pragma("unroll") \
        for (int j = 0; j < 16; ++j) { \
            const int s = (KS)*32 + sgh + j; \
            float w = 0.f; \
            if (s <= sgt) w = s_dtc[s] * fexp_(ct - s_clog[s]); \
            gw[j] = f2bf(gvals[j] * w); \
        } \
        pkA0 = make_uint4(packu2(gw[0],gw[1]), packu2(gw[2],gw[3]), \
                          packu2(gw[4],gw[5]), packu2(gw[6],gw[7])); \
        pkA1 = make_uint4(packu2(gw[8],gw[9]), packu2(gw[10],gw[11]), \
                          packu2(gw[12],gw[13]), packu2(gw[14],gw[15])); \
        pkB  = make_uint4(packu2(xuc[0],xuc[1]), packu2(xuc[2],xuc[3]), \
                          packu2(xuc[4],xuc[5]), packu2(xuc[6],xuc[7])); \
    } while (0)

    YPK(0);
    g0c = *(const uint4*)(gp + sgt*Q + 32 + sgh);
    g1c = *(const uint4*)(gp + sgt*Q + 32 + sgh + 8);
#pragma unroll
    for (int j = 0; j < 8; ++j)
        xuc[j] = xconv[(size_t)(bl0 + 32 + sbc + j)*CONVDIM + h*HEADDIM + sbp];

    // phase 2: acc += (G .* W) @ X (causal)
#pragma unroll
    for (int ks = 0; ks < 4; ++ks) {
        __syncthreads();
        *(uint4*)&Ab[sgt*32 + sgh]     = pkA0;
        *(uint4*)&Ab[sgt*32 + sgh + 8] = pkA1;
        *(uint4*)&Bb[sbp*32 + sbc]     = pkB;
        __syncthreads();
        if (ks < 3) {
            YPK(ks+1);                       // overlaps MFMA(ks) below
            if (ks < 2) {
                g0c = *(const uint4*)(gp + sgt*Q + (ks+2)*32 + sgh);
                g1c = *(const uint4*)(gp + sgt*Q + (ks+2)*32 + sgh + 8);
#pragma unroll
                for (int j = 0; j < 8; ++j)
                    xuc[j] = xconv[(size_t)(bl0 + (ks+2)*32 + sbc + j)*CONVDIM + h*HEADDIM + sbp];
            }
        }
        if (ks <= wv) {
            bf16x8 af[2], bv[4];
            af[0] = *(const bf16x8*)&Ab[(wv*32 +      fr)*32 + fk];
            af[1] = *(const bf16x8*)&Ab[(wv*32 + 16 + fr)*32 + fk];
#pragma unroll
            for (int j = 0; j < 4; ++j)
                bv[j] = *(const bf16x8*)&Bb[(j*16 + fr)*32 + fk];
#pragma unroll
            for (int i = 0; i < 2; ++i)
#pragma unroll
                for (int j = 0; j < 4; ++j)
                    acc[i][j] = MFMA_BF16(af[i], bv[j], acc[i][j]);
        }
    }
#undef YPK

    // epilogue: + D*x, repack to bf16 via LDS (aliases Ab/Bb -> barrier first)
    const float Dh = Dv[h];
    __syncthreads();
    ushort* rp = smu;
#pragma unroll
    for (int i = 0; i < 2; ++i) {
#pragma unroll
        for (int r = 0; r < 4; ++r) {
            const int t = wv*32 + i*16 + fq*4 + r;
            const ushort* xr = xconv + (size_t)(bl0 + t)*CONVDIM + h*HEADDIM;
#pragma unroll
            for (int j = 0; j < 4; ++j) {
                const int p = j*16 + fr;
                rp[t*64 + p] = f2bf(acc[i][j][r] + Dh * bf2f(xr[p]));
            }
        }
    }
#pragma unroll
    for (int k2 = 0; k2 < 4; ++k2) {
        const int row = wv*32 + k2*8 + (ln >> 3);
        uint4 v = *(const uint4*)&rp[row*64 + (ln & 7)*8];
        *(uint4*)(ybf + (size_t)(bl0 + row)*DINNER + h*HEADDIM + (ln & 7)*8) = v;
    }
}

// ---------------- FUSED: gated RMSNorm (in place on ybf)  ||  out_proj_w fp32->bf16
__global__ __launch_bounds__(128) void rms_cast_kernel(
    const ushort* __restrict__ zx, const float* __restrict__ norm_w,
    ushort* __restrict__ ybf, const float* __restrict__ wout,
    ushort* __restrict__ wout_bf)
{
    const int tid = threadIdx.x;
    if (blockIdx.x < BLROWS) {
        const int row = blockIdx.x;
        const ushort* zr = zx + (size_t)row * DINPROJ;
        ushort* yr = ybf + (size_t)row * DINNER;
        float v[12];
        float ss = 0.f;
#pragma unroll
        for (int i = 0; i < 3; ++i) {
            const int o = (tid + i*128) * 4;
            ushort4 yv = *(const ushort4*)(yr + o);
            ushort4 zv = *(const ushort4*)(zr + o);
            float a = bf2f(yv.x) * siluf_(bf2f(zv.x));
            float b = bf2f(yv.y) * siluf_(bf2f(zv.y));
            float cc = bf2f(yv.z) * siluf_(bf2f(zv.z));
            float d = bf2f(yv.w) * siluf_(bf2f(zv.w));
            v[i*4+0]=a; v[i*4+1]=b; v[i*4+2]=cc; v[i*4+3]=d;
            ss += a*a + b*b + cc*cc + d*d;
        }
#pragma unroll
        for (int off = 1; off < 64; off <<= 1) ss += __shfl_xor(ss, off);
        __shared__ float red[2];
        if ((tid & 63) == 0) red[tid >> 6] = ss;
        __syncthreads();
        const float rstd = rsqrtf((red[0] + red[1]) * (1.f/DINNER) + RMS_EPS);
#pragma unroll
        for (int i = 0; i < 3; ++i) {
            const int o = (tid + i*128) * 4;
            float4 wv = *(const float4*)(norm_w + o);
            ushort4 ov = make_ushort4(f2bf(v[i*4+0]*rstd*wv.x), f2bf(v[i*4+1]*rstd*wv.y),
                                      f2bf(v[i*4+2]*rstd*wv.z), f2bf(v[i*4+3]*rstd*wv.w));
            *(ushort4*)(yr + o) = ov;
        }
    } else {
        const int i = (blockIdx.x - BLROWS)*128 + tid;
        const int n4 = DMODEL*DINNER/4;
        if (i < n4) {
            float4 v = ((const float4*)wout)[i];
            ((ushort4*)wout_bf)[i] = make_ushort4(f2bf(v.x), f2bf(v.y), f2bf(v.z), f2bf(v.w));
        }
    }
}

extern "C" void kernel_launch(void* const* d_in, const int* in_sizes, int n_in,
                              void* d_out, int out_size, void* d_ws, size_t ws_size,
                              hipStream_t stream)
{
    const float* feature    = (const float*)d_in[0];
    const float* in_proj_w  = (const float*)d_in[1];
    const float* conv_w     = (const float*)d_in[2];
    const float* conv_b     = (const float*)d_in[3];
    const float* dt_bias    = (const float*)d_in[4];
    const float* A_log      = (const float*)d_in[5];
    const float* Dvec       = (const float*)d_in[6];
    const float* norm_w     = (const float*)d_in[7];
    const float* out_proj_w = (const float*)d_in[8];
    const float* gate1      = (const float*)d_in[9];
    float* out = (float*)d_out;

    ushort* zx    = (ushort*)d_ws;                              // [8192,3352] bf16
    ushort* xconv = zx + (size_t)BLROWS * DINPROJ;              // [8192,1792] bf16
    ushort* ybf   = xconv + (size_t)BLROWS * CONVDIM;           // [8192,1536] bf16
    float* dtraw  = (float*)(ybf + (size_t)BLROWS * DINNER);    // [8192,24]
    float* dtc    = dtraw + (size_t)BLROWS * 24;
    float* clog   = dtc + (size_t)NB * NHEADS * SEQL;
    ushort* Gbuf  = (ushort*)(clog + (size_t)NB * NHEADS * SEQL);  // 2 MB
    ushort* Sbuf  = Gbuf + (size_t)NB * NC * Q * Q;                // 25 MB
    ushort* Abf    = Gbuf;                            // feature bf16 (dead after gemm1)
    ushort* Wbf_in = Gbuf + (size_t)BLROWS * DMODEL;  // in_proj_w bf16 (dead after gemm1)
    ushort* Wbf_out = Sbuf;                           // out_proj_w bf16 (Sbuf dead after ychunk)
    // per-(b,h) scan counters live in the first 384 B of ybf: untouched between
    // cast2 (zeroes them each replay) and gcb_locstate (uses them); ychunk
    // overwrites ybf only after the scans are complete.
    uint* cnt = (uint*)ybf;

    const int n4a = BLROWS*DMODEL/4;
    const int n4b = DINPROJ*DMODEL/4;
    cast2_kernel<<<dim3((n4a + n4b + 255)/256), 256, 0, stream>>>(
        feature, Abf, n4a, in_proj_w, Wbf_in, n4b, cnt);
    // grid = 27 n-blocks x 64 m-blocks = 1728 (divisible by 8 -> bijective XCD swizzle)
    gemm_mfma_bf16o<<<dim3(27*64), 256, 0, stream>>>(Abf, Wbf_in, zx, dtraw,
                                                     BLROWS, DINPROJ, DMODEL);
    // fused conv || dtscan (both depend only on gemm1 output)
    conv_dtscan_kernel<<<dim3(BLROWS/16 + NB*NHEADS*NC), 448, 0, stream>>>(
        zx, conv_w, conv_b, xconv, dtraw, dt_bias, A_log, dtc, clog);
    // fused gcb || locstate+chunkscan (scan tail-fused via device-scope counter)
    gcb_locstate_kernel<<<dim3(2*NC*NB + NC*NHEADS*NB), 256, 0, stream>>>(
        xconv, Gbuf, dtc, clog, Sbuf, cnt);
    ychunk_mfma<<<dim3(NC, NHEADS, NB), 256, 0, stream>>>(xconv, dtc, clog, Gbuf, Sbuf, Dvec, ybf);
    // fused rms || out_proj_w cast (cast writes Sbuf region, disjoint from rms's buffers)
    rms_cast_kernel<<<dim3(BLROWS + (DMODEL*DINNER/4 + 127)/128), 128, 0, stream>>>(
        zx, norm_w, ybf, out_proj_w, Wbf_out);
    // grid = 64 m-tiles x 12 n-tiles = 768 = exactly 3 blocks/CU, balanced
    gemm_mfma<<<dim3(768), 256, 0, stream>>>(ybf, Wbf_out, out,
                                             BLROWS, DMODEL, DINNER, gate1);
}

// Round 9
// 259.960 us; speedup vs baseline: 2.5201x; 2.5201x over previous
//
#include <hip/hip_runtime.h>
#include <cstddef>

#define NB 4
#define SEQL 2048
#define DMODEL 768
#define DSTATE 128
#define HEADDIM 64
#define NHEADS 24
#define DINNER 1536
#define CONVDIM 1792
#define DINPROJ 3352
#define BLROWS (NB*SEQL)
#define RMS_EPS 1e-5f
#define Q 128
#define NC (SEQL/Q)
#define BOFF DINNER
#define COFF (DINNER + DSTATE)
#define BK 64

typedef unsigned int uint;
typedef unsigned short ushort;
typedef __attribute__((ext_vector_type(8))) short bf16x8;
typedef __attribute__((ext_vector_type(4))) float f32x4;

// fast transcendentals: v_exp_f32-based (2 instrs vs ~15 for libm expf)
__device__ __forceinline__ float fexp_(float x){ return __expf(x); }
__device__ __forceinline__ float sigmoidf_(float x){ return 1.f/(1.f+__expf(-x)); }
__device__ __forceinline__ float siluf_(float x){ return x * sigmoidf_(x); }
__device__ __forceinline__ float softplusf_(float x){ return x > 20.f ? x : log1pf(__expf(x)); }

__device__ __forceinline__ ushort f2bf(float f){
    union { float f; uint u; } v; v.f = f;
    uint r = (v.u + 0x7FFFu + ((v.u >> 16) & 1u)) >> 16;
    return (ushort)r;
}
__device__ __forceinline__ float bf2f(ushort s){
    union { uint u; float f; } v; v.u = ((uint)s) << 16;
    return v.f;
}
__device__ __forceinline__ uint pack2(float a, float b){
    return (uint)f2bf(a) | ((uint)f2bf(b) << 16);
}
__device__ __forceinline__ void unpack8(uint4 r, float* o){
    o[0]=bf2f((ushort)(r.x&0xffff)); o[1]=bf2f((ushort)(r.x>>16));
    o[2]=bf2f((ushort)(r.y&0xffff)); o[3]=bf2f((ushort)(r.y>>16));
    o[4]=bf2f((ushort)(r.z&0xffff)); o[5]=bf2f((ushort)(r.z>>16));
    o[6]=bf2f((ushort)(r.w&0xffff)); o[7]=bf2f((ushort)(r.w>>16));
}
__device__ __forceinline__ uint packu2(ushort a, ushort b){
    return (uint)a | ((uint)b << 16);
}

#define GLD16(g, l) __builtin_amdgcn_global_load_lds( \
    (const __attribute__((address_space(1))) void*)(g), \
    (__attribute__((address_space(3))) void*)(l), 16, 0, 0)

#define MFMA_BF16(a, b, c) __builtin_amdgcn_mfma_f32_16x16x32_bf16((a), (b), (c), 0, 0, 0)

// ---------------- fp32 -> bf16 cast, two buffers in one launch
__global__ __launch_bounds__(256) void cast2_kernel(
    const float* __restrict__ a, ushort* __restrict__ oa, int n4a,
    const float* __restrict__ b, ushort* __restrict__ ob, int n4b)
{
    const int i = blockIdx.x*256 + threadIdx.x;
    if (i < n4a) {
        float4 v = ((const float4*)a)[i];
        ((ushort4*)oa)[i] = make_ushort4(f2bf(v.x), f2bf(v.y), f2bf(v.z), f2bf(v.w));
    } else {
        const int j = i - n4a;
        if (j < n4b) {
            float4 v = ((const float4*)b)[j];
            ((ushort4*)ob)[j] = make_ushort4(f2bf(v.x), f2bf(v.y), f2bf(v.z), f2bf(v.w));
        }
    }
}

// ---------------- MFMA GEMM, fp32 out (out_proj): C = A @ W^T.
// BM=128, BN=64, BK=64. grid = 768 = 3 blocks/CU balanced. (R3-proven)
__global__ __launch_bounds__(256) void gemm_mfma(
    const ushort* __restrict__ A, const ushort* __restrict__ W,
    float* __restrict__ C, int M, int N, int K,
    const float* __restrict__ gptr)
{
    __shared__ __align__(16) ushort sm[2*12288];   // 48 KB
    const int tid = threadIdx.x;
    const int wv = tid >> 6, ln = tid & 63;
    const int id = blockIdx.x;
    const int xcd = id & 7;
    const int local = id >> 3;
    const int m0 = (xcd*8 + (local & 7)) * 128;
    const int n0 = (local >> 3) * 64;
    const int wm = (wv >> 1) * 64, wn = (wv & 1) * 32;

    const int sr = ln >> 3;
    const int scol = ((ln & 7) ^ sr) * 8;
    const ushort* gA[4]; ushort* lA[4];
#pragma unroll
    for (int iss = 0; iss < 4; ++iss) {
        gA[iss] = A + (size_t)(m0 + wv*32 + iss*8 + sr) * K + scol;
        lA[iss] = &sm[(wv*32 + iss*8) * BK];
    }
    const ushort* gB[2]; ushort* lB[2];
#pragma unroll
    for (int iss = 0; iss < 2; ++iss) {
        gB[iss] = W + (size_t)(n0 + wv*16 + iss*8 + sr) * K + scol;
        lB[iss] = &sm[8192 + (wv*16 + iss*8) * BK];
    }

    f32x4 acc[4][2];
#pragma unroll
    for (int i = 0; i < 4; ++i)
#pragma unroll
        for (int j = 0; j < 2; ++j) acc[i][j] = (f32x4){0.f, 0.f, 0.f, 0.f};

    const int fr = ln & 15;
    const int fq = ln >> 4;
    const int nt = K / BK;

#pragma unroll
    for (int iss = 0; iss < 4; ++iss) GLD16(gA[iss], lA[iss]);
#pragma unroll
    for (int iss = 0; iss < 2; ++iss) GLD16(gB[iss], lB[iss]);

    for (int kt = 0; kt < nt; ++kt) {
        if (kt + 1 < nt) {
            const int so = ((kt + 1) & 1) * 12288;
            const int ko = (kt + 1) * BK;
#pragma unroll
            for (int iss = 0; iss < 4; ++iss) GLD16(gA[iss] + ko, lA[iss] + so);
#pragma unroll
            for (int iss = 0; iss < 2; ++iss) GLD16(gB[iss] + ko, lB[iss] + so);
            asm volatile("s_waitcnt vmcnt(6)" ::: "memory");
        } else {
            asm volatile("s_waitcnt vmcnt(0)" ::: "memory");
        }
        __builtin_amdgcn_s_barrier();
        const ushort* As = sm + (kt & 1) * 12288;
        const ushort* Bs = As + 8192;
#pragma unroll
        for (int kh = 0; kh < 2; ++kh) {
            const int sw = ((kh*4 + fq) ^ (fr & 7)) * 8;
            bf16x8 af[4], bfr[2];
#pragma unroll
            for (int i = 0; i < 4; ++i)
                af[i] = *(const bf16x8*)&As[(wm + i*16 + fr)*BK + sw];
#pragma unroll
            for (int j = 0; j < 2; ++j)
                bfr[j] = *(const bf16x8*)&Bs[(wn + j*16 + fr)*BK + sw];
#pragma unroll
            for (int i = 0; i < 4; ++i)
#pragma unroll
                for (int j = 0; j < 2; ++j)
                    acc[i][j] = MFMA_BF16(af[i], bfr[j], acc[i][j]);
        }
        __builtin_amdgcn_s_barrier();
    }

    float scale = 1.f;
    if (gptr) scale = sigmoidf_(*gptr);
    const int cn = ln & 15;
    const int cr = (ln >> 4) * 4;
#pragma unroll
    for (int i = 0; i < 4; ++i) {
        const int mb = m0 + wm + i*16 + cr;
#pragma unroll
        for (int j = 0; j < 2; ++j) {
            const int n = n0 + wn + j*16 + cn;
            if (n < N) {
                float* cp = C + (size_t)mb * N + n;
                cp[0*(size_t)N] = acc[i][j].x * scale;
                cp[1*(size_t)N] = acc[i][j].y * scale;
                cp[2*(size_t)N] = acc[i][j].z * scale;
                cp[3*(size_t)N] = acc[i][j].w * scale;
            }
        }
    }
}

// ---------------- MFMA GEMM, bf16 out via LDS repack (in_proj); dt cols -> fp32 dtraw.
// R3-proven 128x128 / BK=64 / 64 KB dbuf / vmcnt(8) / swizzled repack (0 conflicts).
__global__ __launch_bounds__(256) void gemm_mfma_bf16o(
    const ushort* __restrict__ A, const ushort* __restrict__ W,
    ushort* __restrict__ C, float* __restrict__ dtraw, int M, int N, int K)
{
    __shared__ __align__(16) ushort sm[2*128*BK*2];   // 64 KB staging; repack aliases
    const int tid = threadIdx.x;
    const int wv = tid >> 6, ln = tid & 63;
    const int id = blockIdx.x;
    const int xcd = id & 7;
    const int local = id >> 3;
    const int m0 = (xcd*8 + (local & 7)) * 128;
    const int n0 = (local >> 3) * 128;
    const int wm = (wv >> 1) * 64, wn = (wv & 1) * 64;

    const int sr = ln >> 3;
    const int scol = ((ln & 7) ^ sr) * 8;
    const ushort* gA[4]; const ushort* gB[4];
    ushort* lA[4]; ushort* lB[4];
#pragma unroll
    for (int iss = 0; iss < 4; ++iss) {
        const int ra = m0 + wv*32 + iss*8 + sr;
        gA[iss] = A + (size_t)ra * K + scol;
        int rb = n0 + wv*32 + iss*8 + sr; if (rb >= N) rb = N - 1;
        gB[iss] = W + (size_t)rb * K + scol;
        lA[iss] = &sm[(wv*32 + iss*8) * BK];
        lB[iss] = &sm[8192 + (wv*32 + iss*8) * BK];
    }

    f32x4 acc[4][4];
#pragma unroll
    for (int i = 0; i < 4; ++i)
#pragma unroll
        for (int j = 0; j < 4; ++j) acc[i][j] = (f32x4){0.f, 0.f, 0.f, 0.f};

    const int fr = ln & 15;
    const int fq = ln >> 4;
    const int nt = K / BK;

#pragma unroll
    for (int iss = 0; iss < 4; ++iss) {
        GLD16(gA[iss], lA[iss]);
        GLD16(gB[iss], lB[iss]);
    }

    for (int kt = 0; kt < nt; ++kt) {
        if (kt + 1 < nt) {
            const int so = ((kt + 1) & 1) * 16384;
            const int ko = (kt + 1) * BK;
#pragma unroll
            for (int iss = 0; iss < 4; ++iss) {
                GLD16(gA[iss] + ko, lA[iss] + so);
                GLD16(gB[iss] + ko, lB[iss] + so);
            }
            asm volatile("s_waitcnt vmcnt(8)" ::: "memory");
        } else {
            asm volatile("s_waitcnt vmcnt(0)" ::: "memory");
        }
        __builtin_amdgcn_s_barrier();
        const ushort* As = sm + (kt & 1) * 16384;
        const ushort* Bs = As + 8192;
#pragma unroll
        for (int kh = 0; kh < 2; ++kh) {
            const int sw = ((kh*4 + fq) ^ (fr & 7)) * 8;
            bf16x8 af[4], bfr[4];
#pragma unroll
            for (int i = 0; i < 4; ++i)
                af[i] = *(const bf16x8*)&As[(wm + i*16 + fr)*BK + sw];
#pragma unroll
            for (int j = 0; j < 4; ++j)
                bfr[j] = *(const bf16x8*)&Bs[(wn + j*16 + fr)*BK + sw];
#pragma unroll
            for (int i = 0; i < 4; ++i)
#pragma unroll
                for (int j = 0; j < 4; ++j)
                    acc[i][j] = MFMA_BF16(af[i], bfr[j], acc[i][j]);
        }
        __builtin_amdgcn_s_barrier();
    }

    const int cn = ln & 15;
    const int cr = (ln >> 4) * 4;
    __syncthreads();                       // staging LDS dead -> repack
    ushort* rp = sm + wv*4096;             // 64 rows x 64 cols per wave, XOR-swizzled
#pragma unroll
    for (int i = 0; i < 4; ++i)
#pragma unroll
        for (int j = 0; j < 4; ++j) {
            const int colb = j*16 + cn;
#pragma unroll
            for (int r = 0; r < 4; ++r) {
                const int row = i*16 + cr + r;
                rp[row*64 + (((colb >> 3) ^ (row & 7)) * 8) + (colb & 7)] = f2bf(acc[i][j][r]);
            }
        }
    __syncthreads();
#pragma unroll
    for (int k2 = 0; k2 < 8; ++k2) {
        const int row = k2*8 + (ln >> 3);
        const int cg = ln & 7;
        uint4 v = *(const uint4*)&rp[row*64 + ((cg ^ (row & 7)) * 8)];
        const int gm = m0 + wm + row;
        const int gn = n0 + wn + cg*8;
        if (gn + 8 <= N)
            *(uint4*)(C + (size_t)gm*N + gn) = v;
    }
    if (n0 + 128 > N) {
#pragma unroll
        for (int i = 0; i < 4; ++i) {
            const int mb = m0 + wm + i*16 + cr;
#pragma unroll
            for (int j = 0; j < 4; ++j) {
                const int col = (n0 + wn + j*16 + cn) - (N - 24);
                if (col >= 0 && col < 24) {
                    dtraw[(size_t)(mb+0)*24 + col] = acc[i][j].x;
                    dtraw[(size_t)(mb+1)*24 + col] = acc[i][j].y;
                    dtraw[(size_t)(mb+2)*24 + col] = acc[i][j].z;
                    dtraw[(size_t)(mb+3)*24 + col] = acc[i][j].w;
                }
            }
        }
    }
}

// ---------------- FUSED: causal depthwise conv1d+silu  ||  dt softplus+cumsum
__global__ __launch_bounds__(448) void conv_dtscan_kernel(
    const ushort* __restrict__ zx, const float* __restrict__ conv_w,
    const float* __restrict__ conv_b, ushort* __restrict__ xconv,
    const float* __restrict__ dtraw, const float* __restrict__ dt_bias,
    const float* __restrict__ A_log, float* __restrict__ dtc,
    float* __restrict__ clog)
{
    if (blockIdx.x < BLROWS/16) {
        // ---- conv: 16 l-positions per block, sliding register window
        const int c4 = threadIdx.x;
        const int bl0 = blockIdx.x * 16;
        const int l0 = bl0 & (SEQL - 1);
        float w[4][4];
#pragma unroll
        for (int j = 0; j < 4; ++j) {
            float4 wr = *(const float4*)(conv_w + (c4*4 + j)*4);
            w[j][0]=wr.x; w[j][1]=wr.y; w[j][2]=wr.z; w[j][3]=wr.w;
        }
        const float4 bias = *(const float4*)(conv_b + c4*4);
        const ushort* src = zx + DINNER + (size_t)c4*4;
        ushort* dst = xconv + (size_t)c4*4;

        float h0[4], h1[4], h2[4];
        if (l0 == 0) {
#pragma unroll
            for (int ch = 0; ch < 4; ++ch) { h0[ch]=0.f; h1[ch]=0.f; h2[ch]=0.f; }
        } else {
            ushort4 a = *(const ushort4*)(src + (size_t)(bl0-3)*DINPROJ);
            ushort4 b = *(const ushort4*)(src + (size_t)(bl0-2)*DINPROJ);
            ushort4 c = *(const ushort4*)(src + (size_t)(bl0-1)*DINPROJ);
            h0[0]=bf2f(a.x); h0[1]=bf2f(a.y); h0[2]=bf2f(a.z); h0[3]=bf2f(a.w);
            h1[0]=bf2f(b.x); h1[1]=bf2f(b.y); h1[2]=bf2f(b.z); h1[3]=bf2f(b.w);
            h2[0]=bf2f(c.x); h2[1]=bf2f(c.y); h2[2]=bf2f(c.z); h2[3]=bf2f(c.w);
        }
#pragma unroll
        for (int t = 0; t < 16; ++t) {
            ushort4 xv = *(const ushort4*)(src + (size_t)(bl0 + t)*DINPROJ);
            float h3[4] = {bf2f(xv.x), bf2f(xv.y), bf2f(xv.z), bf2f(xv.w)};
            float s0 = fmaf(h3[0], w[0][3], fmaf(h2[0], w[0][2], fmaf(h1[0], w[0][1], fmaf(h0[0], w[0][0], bias.x))));
            float s1 = fmaf(h3[1], w[1][3], fmaf(h2[1], w[1][2], fmaf(h1[1], w[1][1], fmaf(h0[1], w[1][0], bias.y))));
            float s2 = fmaf(h3[2], w[2][3], fmaf(h2[2], w[2][2], fmaf(h1[2], w[2][1], fmaf(h0[2], w[2][0], bias.z))));
            float s3 = fmaf(h3[3], w[3][3], fmaf(h2[3], w[3][2], fmaf(h1[3], w[3][1], fmaf(h0[3], w[3][0], bias.w))));
            ushort4 o = make_ushort4(f2bf(siluf_(s0)), f2bf(siluf_(s1)),
                                     f2bf(siluf_(s2)), f2bf(siluf_(s3)));
            *(ushort4*)(dst + (size_t)(bl0 + t)*CONVDIM) = o;
#pragma unroll
            for (int ch = 0; ch < 4; ++ch) { h0[ch]=h1[ch]; h1[ch]=h2[ch]; h2[ch]=h3[ch]; }
        }
    } else {
        // ---- dtscan: id = c + NC*(h + NHEADS*b)
        const int id = blockIdx.x - BLROWS/16;
        const int c = id & (NC - 1);
        const int h = (id >> 4) % NHEADS;
        const int b = id / (NC * NHEADS);
        const int t = threadIdx.x;
        __shared__ float w0tot;
        float v = 0.f, dtv = 0.f;
        if (t < 128) {
            const int bl = b*SEQL + c*Q + t;
            float draw = dtraw[(size_t)bl*24 + h] + dt_bias[h];
            dtv = softplusf_(draw);
            v = -fexp_(A_log[h]) * dtv;
            const int lane = t & 63;
#pragma unroll
            for (int off = 1; off < 64; off <<= 1) {
                float u = __shfl_up(v, off);
                if (lane >= off) v += u;
            }
            if (t == 63) w0tot = v;
        }
        __syncthreads();
        if (t < 128) {
            if (t >= 64) v += w0tot;
            const int idx = (b*NHEADS + h)*SEQL + c*Q + t;
            dtc[idx] = dtv;
            clog[idx] = v;
        }
    }
}

// ---------------- FUSED: gcb (G = C.B^T)  ||  locstate (local chunk state)
#define ASTR 40
#define BSTR 40
__global__ __launch_bounds__(256) void gcb_locstate_kernel(
    const ushort* __restrict__ xconv, ushort* __restrict__ G,
    const float* __restrict__ dtc, const float* __restrict__ clog,
    ushort* __restrict__ Sloc)
{
    __shared__ __align__(16) char smraw[15872];
    const int tid = threadIdx.x;
    const int wv = tid >> 6, ln = tid & 63;
    const int fr = ln & 15, fq = ln >> 4, fk = fq*8;

    if (blockIdx.x < 2*NC*NB) {
        // ---- gcb: id = thalf + 2*(c + NC*b)
        ushort* Ca = (ushort*)smraw;                 // 64*32
        ushort* Bb = (ushort*)(smraw + 4096);        // 128*32
        const int id = blockIdx.x;
        const int thalf = id & 1;
        const int c = (id >> 1) & (NC - 1);
        const int b = id >> 5;
        const int bl0 = b*SEQL + c*Q;
        const int th0 = thalf*64;

        const int sat = tid & 63,  sac = (tid >> 6)*8;
        const int sbt = tid & 127, sbh = (tid >> 7)*16;

        f32x4 acc[4][2];
#pragma unroll
        for (int i = 0; i < 4; ++i)
#pragma unroll
            for (int j = 0; j < 2; ++j) acc[i][j] = (f32x4){0.f,0.f,0.f,0.f};

        for (int ks = 0; ks < 4; ++ks) {
            uint4 av = *(const uint4*)(xconv + (size_t)(bl0 + th0 + sat)*CONVDIM + COFF + ks*32 + sac);
            const ushort* br = xconv + (size_t)(bl0 + sbt)*CONVDIM + BOFF + ks*32 + sbh;
            uint4 bv0 = *(const uint4*)br;
            uint4 bv1 = *(const uint4*)(br + 8);
            __syncthreads();
            *(uint4*)&Ca[sat*32 + sac] = av;
            *(uint4*)&Bb[sbt*32 + sbh] = bv0;
            *(uint4*)&Bb[sbt*32 + sbh + 8] = bv1;
            __syncthreads();
            bf16x8 av_[4], bv_[2];
#pragma unroll
            for (int i = 0; i < 4; ++i)
                av_[i] = *(const bf16x8*)&Ca[(i*16 + fr)*32 + fk];
#pragma unroll
            for (int j = 0; j < 2; ++j)
                bv_[j] = *(const bf16x8*)&Bb[(wv*32 + j*16 + fr)*32 + fk];
#pragma unroll
            for (int i = 0; i < 4; ++i)
#pragma unroll
                for (int j = 0; j < 2; ++j)
                    acc[i][j] = MFMA_BF16(av_[i], bv_[j], acc[i][j]);
        }
        ushort* gout = G + (size_t)(b*NC + c)*(Q*Q);
#pragma unroll
        for (int i = 0; i < 4; ++i) {
#pragma unroll
            for (int j = 0; j < 2; ++j) {
                const int s = wv*32 + j*16 + fr;
#pragma unroll
                for (int r = 0; r < 4; ++r) {
                    const int t = th0 + i*16 + fq*4 + r;
                    gout[t*Q + s] = f2bf(acc[i][j][r]);
                }
            }
        }
    } else {
        // ---- locstate (R6 pipelined): id = c + NC*(h + NHEADS*b)
        ushort* Ab = (ushort*)smraw;                 // 64*ASTR
        float* sw = (float*)(smraw + 15360);         // 128 floats
        ushort* Bb = (ushort*)(smraw + 5120);        // 128*BSTR
        const int id = blockIdx.x - 2*NC*NB;
        const int c = id & (NC - 1);
        const int h = (id >> 4) % NHEADS;
        const int b = id / (NC * NHEADS);
        const int bh = b*NHEADS + h;
        const int bl0 = b*SEQL + c*Q;

        if (tid < Q) {
            const float ce = clog[(size_t)bh*SEQL + c*Q + (Q-1)];
            const float cs = clog[(size_t)bh*SEQL + c*Q + tid];
            sw[tid] = dtc[(size_t)bh*SEQL + c*Q + tid] * fexp_(ce - cs);
        }

        f32x4 acc[4][2];
#pragma unroll
        for (int i = 0; i < 4; ++i)
#pragma unroll
            for (int j = 0; j < 2; ++j) acc[i][j] = (f32x4){0.f,0.f,0.f,0.f};

        const int ap = tid & 63, aoct = tid >> 6;
        const int bn = tid & 127, bhalf = tid >> 7;

        ushort xrc[8]; ushort buc[16];
#pragma unroll
        for (int j = 0; j < 8; ++j)
            xrc[j] = xconv[(size_t)(bl0 + aoct*8 + j)*CONVDIM + h*HEADDIM + ap];
#pragma unroll
        for (int j = 0; j < 16; ++j)
            buc[j] = xconv[(size_t)(bl0 + bhalf*16 + j)*CONVDIM + BOFF + bn];

        __syncthreads();   // sw visible; raw(0) in regs

        uint4 pkA, pkB0, pkB1;
        {
            float xv[8];
#pragma unroll
            for (int j = 0; j < 8; ++j) xv[j] = bf2f(xrc[j]) * sw[aoct*8 + j];
            pkA = make_uint4(pack2(xv[0],xv[1]), pack2(xv[2],xv[3]),
                             pack2(xv[4],xv[5]), pack2(xv[6],xv[7]));
            pkB0 = make_uint4(packu2(buc[0],buc[1]), packu2(buc[2],buc[3]),
                              packu2(buc[4],buc[5]), packu2(buc[6],buc[7]));
            pkB1 = make_uint4(packu2(buc[8],buc[9]), packu2(buc[10],buc[11]),
                              packu2(buc[12],buc[13]), packu2(buc[14],buc[15]));
        }
#pragma unroll
        for (int j = 0; j < 8; ++j)
            xrc[j] = xconv[(size_t)(bl0 + 32 + aoct*8 + j)*CONVDIM + h*HEADDIM + ap];
#pragma unroll
        for (int j = 0; j < 16; ++j)
            buc[j] = xconv[(size_t)(bl0 + 32 + bhalf*16 + j)*CONVDIM + BOFF + bn];

#pragma unroll
        for (int ks = 0; ks < 4; ++ks) {
            if (ks > 0) __syncthreads();
            *(uint4*)&Ab[ap*ASTR + aoct*8] = pkA;
            *(uint4*)&Bb[bn*BSTR + bhalf*16] = pkB0;
            *(uint4*)&Bb[bn*BSTR + bhalf*16 + 8] = pkB1;
            __syncthreads();
            if (ks < 3) {
                float xv[8];
#pragma unroll
                for (int j = 0; j < 8; ++j) xv[j] = bf2f(xrc[j]) * sw[(ks+1)*32 + aoct*8 + j];
                pkA = make_uint4(pack2(xv[0],xv[1]), pack2(xv[2],xv[3]),
                                 pack2(xv[4],xv[5]), pack2(xv[6],xv[7]));
                pkB0 = make_uint4(packu2(buc[0],buc[1]), packu2(buc[2],buc[3]),
                                  packu2(buc[4],buc[5]), packu2(buc[6],buc[7]));
                pkB1 = make_uint4(packu2(buc[8],buc[9]), packu2(buc[10],buc[11]),
                                  packu2(buc[12],buc[13]), packu2(buc[14],buc[15]));
                if (ks < 2) {
#pragma unroll
                    for (int j = 0; j < 8; ++j)
                        xrc[j] = xconv[(size_t)(bl0 + (ks+2)*32 + aoct*8 + j)*CONVDIM + h*HEADDIM + ap];
#pragma unroll
                    for (int j = 0; j < 16; ++j)
                        buc[j] = xconv[(size_t)(bl0 + (ks+2)*32 + bhalf*16 + j)*CONVDIM + BOFF + bn];
                }
            }
            bf16x8 af[4], bf[2];
#pragma unroll
            for (int i = 0; i < 4; ++i)
                af[i] = *(const bf16x8*)&Ab[(i*16 + fr)*ASTR + fk];
#pragma unroll
            for (int j = 0; j < 2; ++j)
                bf[j] = *(const bf16x8*)&Bb[(wv*32 + j*16 + fr)*BSTR + fk];
#pragma unroll
            for (int i = 0; i < 4; ++i)
#pragma unroll
                for (int j = 0; j < 2; ++j)
                    acc[i][j] = MFMA_BF16(af[i], bf[j], acc[i][j]);
        }
        ushort* dst = Sloc + (size_t)((b*NC + c)*NHEADS + h) * (HEADDIM*DSTATE);
#pragma unroll
        for (int i = 0; i < 4; ++i) {
#pragma unroll
            for (int j = 0; j < 2; ++j) {
                const int n = wv*32 + j*16 + fr;
#pragma unroll
                for (int r = 0; r < 4; ++r) {
                    const int p = i*16 + fq*4 + r;
                    dst[p*DSTATE + n] = f2bf(acc[i][j][r]);
                }
            }
        }
    }
}

// ---------------- in-place sequential prefix over chunk states; 4x p-split
__global__ __launch_bounds__(256) void chunkscan_kernel(
    const float* __restrict__ clog, ushort* __restrict__ S)
{
    const int h = blockIdx.x, b = blockIdx.y, pg = blockIdx.z;
    const int tid = threadIdx.x;
    const int p = pg*16 + (tid >> 4);
    const int n0 = (tid & 15) * 8;
    const int bh = b*NHEADS + h;
    float st[8];
#pragma unroll
    for (int j = 0; j < 8; ++j) st[j] = 0.f;

    uint4 raw = *(uint4*)(S + (size_t)((b*NC + 0)*NHEADS + h) * (HEADDIM*DSTATE) + p*DSTATE + n0);
    for (int c = 0; c < NC; ++c) {
        uint4 cur = raw;
        ushort* base = S + (size_t)((b*NC + c)*NHEADS + h) * (HEADDIM*DSTATE);
        if (c + 1 < NC)
            raw = *(uint4*)(S + (size_t)((b*NC + c + 1)*NHEADS + h) * (HEADDIM*DSTATE) + p*DSTATE + n0);
        const float tc = fexp_(clog[(size_t)bh*SEQL + c*Q + (Q-1)]);
        float lv[8];
        unpack8(cur, lv);
        uint4 pre = make_uint4(pack2(st[0],st[1]), pack2(st[2],st[3]),
                               pack2(st[4],st[5]), pack2(st[6],st[7]));
        *(uint4*)(base + p*DSTATE + n0) = pre;
#pragma unroll
        for (int j = 0; j < 8; ++j) st[j] = fmaf(tc, st[j], lv[j]);
    }
}

// ---------------- Y = causal(G.W)@X + exp(clog)*C@Sp^T + D*x  — MFMA, bf16 out
__global__ __launch_bounds__(256) void ychunk_mfma(
    const ushort* __restrict__ xconv, const float* __restrict__ dtc,
    const float* __restrict__ clog, const ushort* __restrict__ G,
    const ushort* __restrict__ Sp, const float* __restrict__ Dv,
    ushort* __restrict__ ybf)
{
    __shared__ __align__(16) ushort smu[8192];
    ushort* Ab = smu;
    ushort* Bb = smu + 4096;
    __shared__ float s_clog[Q];
    __shared__ float s_dtc[Q];
    const int c = blockIdx.x, h = blockIdx.y, b = blockIdx.z;
    const int tid = threadIdx.x;
    const int wv = tid >> 6, ln = tid & 63;
    const int bh = b*NHEADS + h;
    const int bl0 = b*SEQL + c*Q;
    const int fr = ln & 15, fq = ln >> 4, fk = fq*8;

    if (tid < Q) {
        s_clog[tid] = clog[(size_t)bh*SEQL + c*Q + tid];
        s_dtc[tid]  = dtc [(size_t)bh*SEQL + c*Q + tid];
    }

    f32x4 acc[2][4];
#pragma unroll
    for (int i = 0; i < 2; ++i)
#pragma unroll
        for (int j = 0; j < 4; ++j) acc[i][j] = (f32x4){0.f,0.f,0.f,0.f};

    const int sgt = tid & 127, sgh = (tid >> 7)*16;
    const int sbp = tid & 63,  sbc = (tid >> 6)*8;
    const ushort* spb = Sp + (size_t)((b*NC + c)*NHEADS + h)*(HEADDIM*DSTATE);

    // phase 1: acc = C @ Sp^T  (pipelined loads)
    uint4 cv0c = *(const uint4*)(xconv + (size_t)(bl0 + sgt)*CONVDIM + COFF + sgh);
    uint4 cv1c = *(const uint4*)(xconv + (size_t)(bl0 + sgt)*CONVDIM + COFF + sgh + 8);
    uint4 svc  = *(const uint4*)(spb + sbp*DSTATE + sbc);
#pragma unroll
    for (int ks = 0; ks < 4; ++ks) {
        __syncthreads();
        *(uint4*)&Ab[sgt*32 + sgh]     = cv0c;
        *(uint4*)&Ab[sgt*32 + sgh + 8] = cv1c;
        *(uint4*)&Bb[sbp*32 + sbc] = svc;
        if (ks < 3) {
            const ushort* cr = xconv + (size_t)(bl0 + sgt)*CONVDIM + COFF + (ks+1)*32 + sgh;
            cv0c = *(const uint4*)cr;
            cv1c = *(const uint4*)(cr + 8);
            svc  = *(const uint4*)(spb + sbp*DSTATE + (ks+1)*32 + sbc);
        }
        __syncthreads();
        bf16x8 af[2], bv[4];
        af[0] = *(const bf16x8*)&Ab[(wv*32 +      fr)*32 + fk];
        af[1] = *(const bf16x8*)&Ab[(wv*32 + 16 + fr)*32 + fk];
#pragma unroll
        for (int j = 0; j < 4; ++j)
            bv[j] = *(const bf16x8*)&Bb[(j*16 + fr)*32 + fk];
#pragma unroll
        for (int i = 0; i < 2; ++i)
#pragma unroll
            for (int j = 0; j < 4; ++j)
                acc[i][j] = MFMA_BF16(af[i], bv[j], acc[i][j]);
    }

    // raw(0) for phase 2 (hides under the rescale VALU below)
    const ushort* gp = G + (size_t)(b*NC + c)*(Q*Q);
    uint4 g0c = *(const uint4*)(gp + sgt*Q + sgh);
    uint4 g1c = *(const uint4*)(gp + sgt*Q + sgh + 8);
    ushort xuc[8];
#pragma unroll
    for (int j = 0; j < 8; ++j)
        xuc[j] = xconv[(size_t)(bl0 + sbc + j)*CONVDIM + h*HEADDIM + sbp];

#pragma unroll
    for (int i = 0; i < 2; ++i) {
        const int tb = wv*32 + i*16 + fq*4;
        float e0 = fexp_(s_clog[tb+0]), e1 = fexp_(s_clog[tb+1]);
        float e2 = fexp_(s_clog[tb+2]), e3 = fexp_(s_clog[tb+3]);
#pragma unroll
        for (int j = 0; j < 4; ++j) {
            acc[i][j].x *= e0; acc[i][j].y *= e1; acc[i][j].z *= e2; acc[i][j].w *= e3;
        }
    }

    const float ct = s_clog[sgt];

    uint4 pkA0, pkA1, pkB;
#define YPK(KS) do { \
        float gvals[16]; \
        unpack8(g0c, gvals); \
        unpack8(g1c, gvals + 8); \
        ushort gw[16]; \
        _Pragma("unroll") \
        for (int j = 0; j < 16; ++j) { \
            const int s = (KS)*32 + sgh + j; \
            float w = 0.f; \
            if (s <= sgt) w = s_dtc[s] * fexp_(ct - s_clog[s]); \
            gw[j] = f2bf(gvals[j] * w); \
        } \
        pkA0 = make_uint4(packu2(gw[0],gw[1]), packu2(gw[2],gw[3]), \
                          packu2(gw[4],gw[5]), packu2(gw[6],gw[7])); \
        pkA1 = make_uint4(packu2(gw[8],gw[9]), packu2(gw[10],gw[11]), \
                          packu2(gw[12],gw[13]), packu2(gw[14],gw[15])); \
        pkB  = make_uint4(packu2(xuc[0],xuc[1]), packu2(xuc[2],xuc[3]), \
                          packu2(xuc[4],xuc[5]), packu2(xuc[6],xuc[7])); \
    } while (0)

    YPK(0);
    g0c = *(const uint4*)(gp + sgt*Q + 32 + sgh);
    g1c = *(const uint4*)(gp + sgt*Q + 32 + sgh + 8);
#pragma unroll
    for (int j = 0; j < 8; ++j)
        xuc[j] = xconv[(size_t)(bl0 + 32 + sbc + j)*CONVDIM + h*HEADDIM + sbp];

    // phase 2: acc += (G .* W) @ X (causal)
#pragma unroll
    for (int ks = 0; ks < 4; ++ks) {
        __syncthreads();
        *(uint4*)&Ab[sgt*32 + sgh]     = pkA0;
        *(uint4*)&Ab[sgt*32 + sgh + 8] = pkA1;
        *(uint4*)&Bb[sbp*32 + sbc]     = pkB;
        __syncthreads();
        if (ks < 3) {
            YPK(ks+1);                       // overlaps MFMA(ks) below
            if (ks < 2) {
                g0c = *(const uint4*)(gp + sgt*Q + (ks+2)*32 + sgh);
                g1c = *(const uint4*)(gp + sgt*Q + (ks+2)*32 + sgh + 8);
#pragma unroll
                for (int j = 0; j < 8; ++j)
                    xuc[j] = xconv[(size_t)(bl0 + (ks+2)*32 + sbc + j)*CONVDIM + h*HEADDIM + sbp];
            }
        }
        if (ks <= wv) {
            bf16x8 af[2], bv[4];
            af[0] = *(const bf16x8*)&Ab[(wv*32 +      fr)*32 + fk];
            af[1] = *(const bf16x8*)&Ab[(wv*32 + 16 + fr)*32 + fk];
#pragma unroll
            for (int j = 0; j < 4; ++j)
                bv[j] = *(const bf16x8*)&Bb[(j*16 + fr)*32 + fk];
#pragma unroll
            for (int i = 0; i < 2; ++i)
#pragma unroll
                for (int j = 0; j < 4; ++j)
                    acc[i][j] = MFMA_BF16(af[i], bv[j], acc[i][j]);
        }
    }
#undef YPK

    // epilogue: + D*x, repack to bf16 via LDS (aliases Ab/Bb -> barrier first)
    const float Dh = Dv[h];
    __syncthreads();
    ushort* rp = smu;
#pragma unroll
    for (int i = 0; i < 2; ++i) {
#pragma unroll
        for (int r = 0; r < 4; ++r) {
            const int t = wv*32 + i*16 + fq*4 + r;
            const ushort* xr = xconv + (size_t)(bl0 + t)*CONVDIM + h*HEADDIM;
#pragma unroll
            for (int j = 0; j < 4; ++j) {
                const int p = j*16 + fr;
                rp[t*64 + p] = f2bf(acc[i][j][r] + Dh * bf2f(xr[p]));
            }
        }
    }
#pragma unroll
    for (int k2 = 0; k2 < 4; ++k2) {
        const int row = wv*32 + k2*8 + (ln >> 3);
        uint4 v = *(const uint4*)&rp[row*64 + (ln & 7)*8];
        *(uint4*)(ybf + (size_t)(bl0 + row)*DINNER + h*HEADDIM + (ln & 7)*8) = v;
    }
}

// ---------------- FUSED: gated RMSNorm (in place on ybf)  ||  out_proj_w fp32->bf16
__global__ __launch_bounds__(128) void rms_cast_kernel(
    const ushort* __restrict__ zx, const float* __restrict__ norm_w,
    ushort* __restrict__ ybf, const float* __restrict__ wout,
    ushort* __restrict__ wout_bf)
{
    const int tid = threadIdx.x;
    if (blockIdx.x < BLROWS) {
        const int row = blockIdx.x;
        const ushort* zr = zx + (size_t)row * DINPROJ;
        ushort* yr = ybf + (size_t)row * DINNER;
        float v[12];
        float ss = 0.f;
#pragma unroll
        for (int i = 0; i < 3; ++i) {
            const int o = (tid + i*128) * 4;
            ushort4 yv = *(const ushort4*)(yr + o);
            ushort4 zv = *(const ushort4*)(zr + o);
            float a = bf2f(yv.x) * siluf_(bf2f(zv.x));
            float b = bf2f(yv.y) * siluf_(bf2f(zv.y));
            float cc = bf2f(yv.z) * siluf_(bf2f(zv.z));
            float d = bf2f(yv.w) * siluf_(bf2f(zv.w));
            v[i*4+0]=a; v[i*4+1]=b; v[i*4+2]=cc; v[i*4+3]=d;
            ss += a*a + b*b + cc*cc + d*d;
        }
#pragma unroll
        for (int off = 1; off < 64; off <<= 1) ss += __shfl_xor(ss, off);
        __shared__ float red[2];
        if ((tid & 63) == 0) red[tid >> 6] = ss;
        __syncthreads();
        const float rstd = rsqrtf((red[0] + red[1]) * (1.f/DINNER) + RMS_EPS);
#pragma unroll
        for (int i = 0; i < 3; ++i) {
            const int o = (tid + i*128) * 4;
            float4 wv = *(const float4*)(norm_w + o);
            ushort4 ov = make_ushort4(f2bf(v[i*4+0]*rstd*wv.x), f2bf(v[i*4+1]*rstd*wv.y),
                                      f2bf(v[i*4+2]*rstd*wv.z), f2bf(v[i*4+3]*rstd*wv.w));
            *(ushort4*)(yr + o) = ov;
        }
    } else {
        const int i = (blockIdx.x - BLROWS)*128 + tid;
        const int n4 = DMODEL*DINNER/4;
        if (i < n4) {
            float4 v = ((const float4*)wout)[i];
            ((ushort4*)wout_bf)[i] = make_ushort4(f2bf(v.x), f2bf(v.y), f2bf(v.z), f2bf(v.w));
        }
    }
}

extern "C" void kernel_launch(void* const* d_in, const int* in_sizes, int n_in,
                              void* d_out, int out_size, void* d_ws, size_t ws_size,
                              hipStream_t stream)
{
    const float* feature    = (const float*)d_in[0];
    const float* in_proj_w  = (const float*)d_in[1];
    const float* conv_w     = (const float*)d_in[2];
    const float* conv_b     = (const float*)d_in[3];
    const float* dt_bias    = (const float*)d_in[4];
    const float* A_log      = (const float*)d_in[5];
    const float* Dvec       = (const float*)d_in[6];
    const float* norm_w     = (const float*)d_in[7];
    const float* out_proj_w = (const float*)d_in[8];
    const float* gate1      = (const float*)d_in[9];
    float* out = (float*)d_out;

    ushort* zx    = (ushort*)d_ws;                              // [8192,3352] bf16
    ushort* xconv = zx + (size_t)BLROWS * DINPROJ;              // [8192,1792] bf16
    ushort* ybf   = xconv + (size_t)BLROWS * CONVDIM;           // [8192,1536] bf16
    float* dtraw  = (float*)(ybf + (size_t)BLROWS * DINNER);    // [8192,24]
    float* dtc    = dtraw + (size_t)BLROWS * 24;
    float* clog   = dtc + (size_t)NB * NHEADS * SEQL;
    ushort* Gbuf  = (ushort*)(clog + (size_t)NB * NHEADS * SEQL);  // 2 MB
    ushort* Sbuf  = Gbuf + (size_t)NB * NC * Q * Q;                // 25 MB
    ushort* Abf    = Gbuf;                            // feature bf16 (dead after gemm1)
    ushort* Wbf_in = Gbuf + (size_t)BLROWS * DMODEL;  // in_proj_w bf16 (dead after gemm1)
    ushort* Wbf_out = Sbuf;                           // out_proj_w bf16 (Sbuf dead after ychunk)

    const int n4a = BLROWS*DMODEL/4;
    const int n4b = DINPROJ*DMODEL/4;
    cast2_kernel<<<dim3((n4a + n4b + 255)/256), 256, 0, stream>>>(
        feature, Abf, n4a, in_proj_w, Wbf_in, n4b);
    // grid = 27 n-blocks x 64 m-blocks = 1728 (divisible by 8 -> bijective XCD swizzle)
    gemm_mfma_bf16o<<<dim3(27*64), 256, 0, stream>>>(Abf, Wbf_in, zx, dtraw,
                                                     BLROWS, DINPROJ, DMODEL);
    // fused conv || dtscan (both depend only on gemm1 output)
    conv_dtscan_kernel<<<dim3(BLROWS/16 + NB*NHEADS*NC), 448, 0, stream>>>(
        zx, conv_w, conv_b, xconv, dtraw, dt_bias, A_log, dtc, clog);
    // fused gcb || locstate (both depend only on xconv/dtc/clog)
    gcb_locstate_kernel<<<dim3(2*NC*NB + NC*NHEADS*NB), 256, 0, stream>>>(
        xconv, Gbuf, dtc, clog, Sbuf);
    chunkscan_kernel<<<dim3(NHEADS, NB, 4), 256, 0, stream>>>(clog, Sbuf);
    ychunk_mfma<<<dim3(NC, NHEADS, NB), 256, 0, stream>>>(xconv, dtc, clog, Gbuf, Sbuf, Dvec, ybf);
    // fused rms || out_proj_w cast (cast writes Sbuf region, disjoint from rms's buffers)
    rms_cast_kernel<<<dim3(BLROWS + (DMODEL*DINNER/4 + 127)/128), 128, 0, stream>>>(
        zx, norm_w, ybf, out_proj_w, Wbf_out);
    // grid = 64 m-tiles x 12 n-tiles = 768 = exactly 3 blocks/CU, balanced
    gemm_mfma<<<dim3(768), 256, 0, stream>>>(ybf, Wbf_out, out,
                                             BLROWS, DMODEL, DINNER, gate1);
}